// Round 2
// baseline (551.399 us; speedup 1.0000x reference)
//
#include <hip/hip_runtime.h>

#define Nn 100000
#define Ee 1600000
#define IND 256
#define HD 128
#define NCLS 40
#define NBLK 391   // ceil(Nn/256)

typedef _Float16 f16;
typedef f16 f16x8 __attribute__((ext_vector_type(8)));
typedef f16 f16x4 __attribute__((ext_vector_type(4)));
typedef float f32x4 __attribute__((ext_vector_type(4)));

// ---------------------------------------------------------------------------
// CSR build: histogram -> exclusive scan -> bucket scatter.
// ---------------------------------------------------------------------------
extern "C" __global__ void __launch_bounds__(256)
k_hist(const int* __restrict__ ei, int* __restrict__ counts) {
    int e = blockIdx.x * 256 + threadIdx.x;
    if (e < Ee) atomicAdd(&counts[ei[Ee + e]], 1);
}

extern "C" __global__ void __launch_bounds__(256)
k_scan1(const int* __restrict__ counts, int* __restrict__ bsum) {
    __shared__ int s[256];
    int t = threadIdx.x;
    int i = blockIdx.x * 256 + t;
    s[t] = (i < Nn) ? counts[i] : 0;
    __syncthreads();
    for (int d = 128; d > 0; d >>= 1) {
        if (t < d) s[t] += s[t + d];
        __syncthreads();
    }
    if (t == 0) bsum[blockIdx.x] = s[0];
}

extern "C" __global__ void __launch_bounds__(512)
k_scan2(int* __restrict__ bsum) {
    __shared__ int s[512];
    int t = threadIdx.x;
    int v = (t < NBLK) ? bsum[t] : 0;
    s[t] = v;
    __syncthreads();
    for (int d = 1; d < 512; d <<= 1) {
        int x = (t >= d) ? s[t - d] : 0;
        __syncthreads();
        s[t] += x;
        __syncthreads();
    }
    if (t < NBLK) bsum[t] = s[t] - v;
}

extern "C" __global__ void __launch_bounds__(256)
k_scan3(const int* __restrict__ counts, const int* __restrict__ bsum,
        int* __restrict__ offsets) {
    __shared__ int s[256];
    int t = threadIdx.x;
    int i = blockIdx.x * 256 + t;
    int v = (i < Nn) ? counts[i] : 0;
    s[t] = v;
    __syncthreads();
    for (int d = 1; d < 256; d <<= 1) {
        int x = (t >= d) ? s[t - d] : 0;
        __syncthreads();
        s[t] += x;
        __syncthreads();
    }
    if (i < Nn) offsets[i] = bsum[blockIdx.x] + s[t] - v;
    if (i == 0) offsets[Nn] = Ee;
}

// scatter: slot allocation via atomicSub on counts (counts dead after scan3;
// within-segment order is irrelevant for a sum).
extern "C" __global__ void __launch_bounds__(256)
k_scatter(const int* __restrict__ ei, const int* __restrict__ offsets,
          int* __restrict__ counts, int* __restrict__ bucket) {
    int e = blockIdx.x * 256 + threadIdx.x;
    if (e >= Ee) return;
    int dst = ei[Ee + e];
    int r = atomicSub(&counts[dst], 1);
    bucket[offsets[dst] + r - 1] = ei[e];
}

// ---------------------------------------------------------------------------
// Fused prep: weight pack (idx < 120832) + emb fp32->f16 (rest).
// wpack layout: P[((ft*KT+kt)*64+L)*8+j] = W[kt*32+(L>>4)*8+j][ft*16+(L&15)]
// Both ranges are multiples of 256 -> wave-uniform branches.
// ---------------------------------------------------------------------------
extern "C" __global__ void __launch_bounds__(256)
k_prep(const float* __restrict__ wx1, const float* __restrict__ wx2,
       const float* __restrict__ wa1, const float* __restrict__ wa2,
       const float* __restrict__ ww1, const float* __restrict__ wc,
       f16* __restrict__ wp,
       const float* __restrict__ emb, f16* __restrict__ embh) {
    int idx = blockIdx.x * 256 + threadIdx.x;
    if (idx >= 120832) {
        // emb conversion: 8 elems/thread
        int i = idx - 120832;
        const float4* p = (const float4*)emb + (size_t)i * 2;
        float4 a = p[0], b = p[1];
        f16x8 h;
        h[0] = (f16)a.x; h[1] = (f16)a.y; h[2] = (f16)a.z; h[3] = (f16)a.w;
        h[4] = (f16)b.x; h[5] = (f16)b.y; h[6] = (f16)b.z; h[7] = (f16)b.w;
        *(f16x8*)(embh + (size_t)i * 8) = h;
        return;
    }
    const float* W;
    int K, base;
    if (idx < 32768)       { W = wx1; K = 256; base = 0; }
    else if (idx < 49152)  { W = wx2; K = 128; base = 32768; }
    else if (idx < 65536)  { W = wa1; K = 128; base = 49152; }
    else if (idx < 81920)  { W = wa2; K = 128; base = 65536; }
    else if (idx < 114688) { W = ww1; K = 256; base = 81920; }
    else {
        // wc: [HD][NCLS] row-major, padded to 48 cols (3 ftiles), KT=4
        int local = idx - 114688;   // < 6144
        int j = local & 7;
        int L = (local >> 3) & 63;
        int kt = (local >> 9) & 3;
        int ft = local / 2048;
        int k = kt * 32 + (L >> 4) * 8 + j;
        int n = ft * 16 + (L & 15);
        wp[idx] = (n < NCLS) ? (f16)wc[k * NCLS + n] : (f16)0.f;
        return;
    }
    int local = idx - base;
    int KT = K >> 5;
    int j = local & 7;
    int L = (local >> 3) & 63;
    int kt = (local >> 9) % KT;
    int ft = local / (512 * KT);
    int k = kt * 32 + (L >> 4) * 8 + j;
    int n = ft * 16 + (L & 15);
    wp[idx] = (f16)W[k * HD + n];
}

// ---------------------------------------------------------------------------
// Gather-mean over f16 embeddings: one wave per node, quarter-wave per edge
// slot (16 lanes x f16x8 = 256B row). Bucket indices for the whole segment
// are preloaded in ONE coalesced read (bucket[beg+lane]) and distributed via
// __shfl -> removes the dependent bucket load from the gather critical path.
// 4 row-gathers in flight. deg>64 handled by a (rare) fallback loop.
// Output: MFMA A-frag packed layout (unchanged):
//   harawp[((nt*4+kt)*64 + m + 16*q2)*8 + j],  col = kt*32 + q2*8 + j.
// ---------------------------------------------------------------------------
extern "C" __global__ void __launch_bounds__(256)
k_gather(const int* __restrict__ offsets, const int* __restrict__ bucket,
         const f16* __restrict__ embh, f16* __restrict__ harawp) {
    int t = threadIdx.x;
    int lane = t & 63;
    int node = blockIdx.x * 4 + (t >> 6);
    int q = lane >> 4;          // quarter-wave id: edge slot
    int cl = (lane & 15) * 8;   // column base (8 cols per lane)

    int beg = offsets[node];
    int end = offsets[node + 1];
    int deg = end - beg;

    // one coalesced load covers the first 64 edge indices of this node
    int myidx = (lane < deg) ? bucket[beg + lane] : 0;

    float s[8];
#pragma unroll
    for (int j = 0; j < 8; j++) s[j] = 0.f;

    int dlim = (deg < 64) ? deg : 64;
    int e = q;
    for (; e + 12 < dlim; e += 16) {       // 4 gathers in flight
        int a0 = __shfl(myidx, e);
        int a1 = __shfl(myidx, e + 4);
        int a2 = __shfl(myidx, e + 8);
        int a3 = __shfl(myidx, e + 12);
        f16x8 v0 = *(const f16x8*)(embh + (size_t)a0 * HD + cl);
        f16x8 v1 = *(const f16x8*)(embh + (size_t)a1 * HD + cl);
        f16x8 v2 = *(const f16x8*)(embh + (size_t)a2 * HD + cl);
        f16x8 v3 = *(const f16x8*)(embh + (size_t)a3 * HD + cl);
#pragma unroll
        for (int j = 0; j < 8; j++)
            s[j] += ((float)v0[j] + (float)v1[j]) + ((float)v2[j] + (float)v3[j]);
    }
    for (; e + 4 < dlim; e += 8) {         // 2 in flight
        int a0 = __shfl(myidx, e);
        int a1 = __shfl(myidx, e + 4);
        f16x8 v0 = *(const f16x8*)(embh + (size_t)a0 * HD + cl);
        f16x8 v1 = *(const f16x8*)(embh + (size_t)a1 * HD + cl);
#pragma unroll
        for (int j = 0; j < 8; j++) s[j] += (float)v0[j] + (float)v1[j];
    }
    if (e < dlim) {
        int a0 = __shfl(myidx, e);
        f16x8 v0 = *(const f16x8*)(embh + (size_t)a0 * HD + cl);
#pragma unroll
        for (int j = 0; j < 8; j++) s[j] += (float)v0[j];
    }
    // rare tail: degree beyond 64 (Poisson(16) -> ~never, but correct)
    for (int i = beg + 64 + q; i < end; i += 4) {
        int a0 = bucket[i];
        f16x8 v0 = *(const f16x8*)(embh + (size_t)a0 * HD + cl);
#pragma unroll
        for (int j = 0; j < 8; j++) s[j] += (float)v0[j];
    }

    // reduce across the 4 quarter-waves (lanes l, l+16, l+32, l+48)
#pragma unroll
    for (int j = 0; j < 8; j++) {
        s[j] += __shfl_down(s[j], 32);
        s[j] += __shfl_down(s[j], 16);
    }

    if (lane < 16) {
        float inv = 1.0f / fmaxf((float)deg, 1.0f);
        f16x8 h;
#pragma unroll
        for (int j = 0; j < 8; j++) h[j] = (f16)(s[j] * inv);
        int nt = node >> 4, m = node & 15;
        int kt = lane >> 2, q2 = lane & 3;
        *(f16x8*)(harawp + (((nt * 4 + kt) * 64 + m + 16 * q2) * 8)) = h;
    }
}

// ---------------------------------------------------------------------------
// Fused MLP, all-MFMA. 32 nodes/block, 4 waves: mt=wid>>1 (node 16-tile),
// fh=wid&1 (feature half). A-frags: x + haraw direct from global (coalesced,
// f16-packed for haraw, fp32+cvt for x); B-frags: packed weights from global
// (L2-hot). LDS 24KB (shared t1p/t2p/h2p + hxp + hap) -> 6 blocks/CU.
// Residual hx+ha kept in registers (same C-tile mapping across steps).
// ---------------------------------------------------------------------------
extern "C" __global__ void __launch_bounds__(256, 6)
linkx_mlp(const float* __restrict__ x, const f16* __restrict__ harawp,
          const f16* __restrict__ wx1p, const float* __restrict__ bx1,
          const f16* __restrict__ wx2p, const float* __restrict__ bx2,
          const f16* __restrict__ wa1p, const float* __restrict__ ba1,
          const f16* __restrict__ wa2p, const float* __restrict__ ba2,
          const f16* __restrict__ ww1p, const float* __restrict__ bw1,
          const f16* __restrict__ wcp, const float* __restrict__ bc,
          float* __restrict__ out) {
    __shared__ __align__(16) f16 shr[4096];   // t1p / t2p / h2p (8KB shared)
    __shared__ __align__(16) f16 hxp[4096];   // hx packed (8KB)
    __shared__ __align__(16) f16 hap[4096];   // ha packed (8KB)

    const int t = threadIdx.x;
    const int node0 = blockIdx.x * 32;
    const int lane = t & 63;
    const int wid = t >> 6;
    const int mt = wid >> 1;
    const int fh = wid & 1;

    f32x4 acc[4];
    float rreg[4][4];   // hx+ha residual, same C-tile as acc

#define INIT_ACC(BIAS)                                                    \
    _Pragma("unroll")                                                     \
    for (int q = 0; q < 4; q++) {                                         \
        float bv = (BIAS)[(fh * 4 + q) * 16 + (lane & 15)];               \
        acc[q][0] = bv; acc[q][1] = bv; acc[q][2] = bv; acc[q][3] = bv;   \
    }

#define GEMM_K128(APACK, BP)                                                  \
    _Pragma("unroll")                                                         \
    for (int kt = 0; kt < 4; kt++) {                                          \
        f16x8 a = *(const f16x8*)((APACK) + ((mt * 4 + kt) * 64 + lane) * 8); \
        _Pragma("unroll")                                                     \
        for (int q = 0; q < 4; q++) {                                         \
            f16x8 b = *(const f16x8*)((BP) + (((fh*4+q)*4 + kt)*64 + lane)*8);\
            acc[q] = __builtin_amdgcn_mfma_f32_16x16x32_f16(a, b, acc[q], 0, 0, 0); \
        }                                                                     \
    }

    // Epilogue -> packed LDS dst; MODE 0: relu, 1: no relu + rreg=v,
    // 2: no relu + rreg+=v, 3: h=relu(acc); v=relu(h+rreg)
#define EPILOGUE(MODE, PDST)                                                  \
    _Pragma("unroll")                                                         \
    for (int q = 0; q < 4; q++) {                                             \
        int f = (fh * 4 + q) * 16 + (lane & 15);                              \
        int kt2 = f >> 5, q2 = (f >> 3) & 3, j2 = f & 7;                      \
        _Pragma("unroll")                                                     \
        for (int r = 0; r < 4; r++) {                                         \
            int n = (lane >> 4) * 4 + r;                                      \
            float v = acc[q][r];                                              \
            if (MODE == 0) v = fmaxf(v, 0.f);                                 \
            if (MODE == 1) rreg[q][r] = v;                                    \
            if (MODE == 2) rreg[q][r] += v;                                   \
            if (MODE == 3) v = fmaxf(fmaxf(v, 0.f) + rreg[q][r], 0.f);        \
            (PDST)[((mt * 4 + kt2) * 64 + n + 16 * q2) * 8 + j2] = (f16)v;    \
        }                                                                     \
    }

    // step2: t1 = relu(x @ wx1 + bx1), K=256; A from global x (fp32->f16)
    INIT_ACC(bx1)
#pragma unroll
    for (int kt = 0; kt < 8; kt++) {
        const float* xr = x + (size_t)(node0 + mt * 16 + (lane & 15)) * IND
                            + kt * 32 + (lane >> 4) * 8;
        float4 u0 = *(const float4*)(xr);
        float4 u1 = *(const float4*)(xr + 4);
        f16x8 a;
        a[0] = (f16)u0.x; a[1] = (f16)u0.y; a[2] = (f16)u0.z; a[3] = (f16)u0.w;
        a[4] = (f16)u1.x; a[5] = (f16)u1.y; a[6] = (f16)u1.z; a[7] = (f16)u1.w;
#pragma unroll
        for (int q = 0; q < 4; q++) {
            f16x8 b = *(const f16x8*)(wx1p + (((fh*4+q)*8 + kt)*64 + lane)*8);
            acc[q] = __builtin_amdgcn_mfma_f32_16x16x32_f16(a, b, acc[q], 0, 0, 0);
        }
    }
    EPILOGUE(0, shr)          // t1p
    __syncthreads();

    // step3: hx = t1 @ wx2 + bx2 -> hxp, rreg = hx
    INIT_ACC(bx2)
    GEMM_K128(shr, wx2p)
    EPILOGUE(1, hxp)
    __syncthreads();          // t1p reads done -> shr reusable

    // step5: t2 = relu(haraw @ wa1 + ba1); A direct from global packed f16
    INIT_ACC(ba1)
    {
        int ntb = (node0 >> 4) + mt;
#pragma unroll
        for (int kt = 0; kt < 4; kt++) {
            f16x8 a = *(const f16x8*)(harawp + ((ntb * 4 + kt) * 64 + lane) * 8);
#pragma unroll
            for (int q = 0; q < 4; q++) {
                f16x8 b = *(const f16x8*)(wa1p + (((fh*4+q)*4 + kt)*64 + lane)*8);
                acc[q] = __builtin_amdgcn_mfma_f32_16x16x32_f16(a, b, acc[q], 0, 0, 0);
            }
        }
    }
    EPILOGUE(0, shr)          // t2p
    __syncthreads();

    // step6: ha = t2 @ wa2 + ba2 -> hap, rreg += ha
    INIT_ACC(ba2)
    GEMM_K128(shr, wa2p)
    EPILOGUE(2, hap)
    __syncthreads();          // t2p reads done -> shr reusable

    // step7+8: h2 = relu(relu([hx|ha] @ ww1 + bw1) + hx + ha) -> h2p
    INIT_ACC(bw1)
#pragma unroll
    for (int kt = 0; kt < 8; kt++) {
        const f16* ap = (kt < 4) ? (hxp + ((mt * 4 + kt) * 64 + lane) * 8)
                                 : (hap + ((mt * 4 + (kt - 4)) * 64 + lane) * 8);
        f16x8 a = *(const f16x8*)ap;
#pragma unroll
        for (int q = 0; q < 4; q++) {
            f16x8 b = *(const f16x8*)(ww1p + (((fh*4+q)*8 + kt)*64 + lane)*8);
            acc[q] = __builtin_amdgcn_mfma_f32_16x16x32_f16(a, b, acc[q], 0, 0, 0);
        }
    }
    EPILOGUE(3, shr)          // h2p
    __syncthreads();

    // step9: logits = h2 @ wc + bc (MFMA, 3 ftiles: fh0 -> {0,2}, fh1 -> {1})
    {
        int nft = (fh == 0) ? 2 : 1;
#pragma unroll 2
        for (int ii = 0; ii < nft; ii++) {
            int ft = (ii == 0) ? fh : 2;
            int f = ft * 16 + (lane & 15);
            f32x4 c;
            float bv = (f < NCLS) ? bc[f] : 0.f;
            c[0] = bv; c[1] = bv; c[2] = bv; c[3] = bv;
#pragma unroll
            for (int kt = 0; kt < 4; kt++) {
                f16x8 a = *(const f16x8*)(shr + ((mt * 4 + kt) * 64 + lane) * 8);
                f16x8 b = *(const f16x8*)(wcp + ((ft * 4 + kt) * 64 + lane) * 8);
                c = __builtin_amdgcn_mfma_f32_16x16x32_f16(a, b, c, 0, 0, 0);
            }
            if (f < NCLS) {
#pragma unroll
                for (int r = 0; r < 4; r++) {
                    int n = node0 + mt * 16 + (lane >> 4) * 4 + r;
                    out[(size_t)n * NCLS + f] = c[r];
                }
            }
        }
    }
}

extern "C" void kernel_launch(void* const* d_in, const int* in_sizes, int n_in,
                              void* d_out, int out_size, void* d_ws, size_t ws_size,
                              hipStream_t stream) {
    const float* x   = (const float*)d_in[0];
    const int*   ei  = (const int*)d_in[1];
    const float* emb = (const float*)d_in[2];
    const float* wx1 = (const float*)d_in[3];
    const float* bx1 = (const float*)d_in[4];
    const float* wx2 = (const float*)d_in[5];
    const float* bx2 = (const float*)d_in[6];
    const float* wa1 = (const float*)d_in[7];
    const float* ba1 = (const float*)d_in[8];
    const float* wa2 = (const float*)d_in[9];
    const float* ba2 = (const float*)d_in[10];
    const float* ww1 = (const float*)d_in[11];
    const float* bw1 = (const float*)d_in[12];
    const float* wc  = (const float*)d_in[13];
    const float* bc  = (const float*)d_in[14];
    float* out = (float*)d_out;

    int* ws = (int*)d_ws;
    int* counts  = ws;                 // [Nn]  (also scatter slot allocator)
    int* offsets = ws + 2 * Nn;        // [Nn+1]
    int* bsum    = ws + 3 * Nn + 16;   // [NBLK]
    int* bucket  = ws + 3 * Nn + 512;  // [Ee]
    f16* wp      = (f16*)(ws + 3 * Nn + 512 + Ee);  // 120832 f16 (16B aligned)
    f16* wx1p = wp;                 // 32768
    f16* wx2p = wp + 32768;         // 16384
    f16* wa1p = wp + 49152;         // 16384
    f16* wa2p = wp + 65536;         // 16384
    f16* ww1p = wp + 81920;         // 32768
    f16* wcp  = wp + 114688;        // 6144
    f16* harawp = wp + 131072;                       // [Nn*HD] f16, A-packed
    f16* embh   = harawp + (size_t)Nn * HD;          // [Nn*HD] f16, linear

    hipMemsetAsync(ws, 0, (size_t)Nn * sizeof(int), stream);

    // prep: wpack (472 blocks worth) + embconv (6250 blocks worth), fused
    k_prep<<<6722, 256, 0, stream>>>(wx1, wx2, wa1, wa2, ww1, wc, wp, emb, embh);
    k_hist<<<Ee / 256, 256, 0, stream>>>(ei, counts);
    k_scan1<<<NBLK, 256, 0, stream>>>(counts, bsum);
    k_scan2<<<1, 512, 0, stream>>>(bsum);
    k_scan3<<<NBLK, 256, 0, stream>>>(counts, bsum, offsets);
    k_scatter<<<Ee / 256, 256, 0, stream>>>(ei, offsets, counts, bucket);
    k_gather<<<Nn / 4, 256, 0, stream>>>(offsets, bucket, embh, harawp);

    linkx_mlp<<<Nn / 32, 256, 0, stream>>>(x, harawp,
                                           wx1p, bx1, wx2p, bx2,
                                           wa1p, ba1, wa2p, ba2,
                                           ww1p, bw1, wcp, bc, out);
}

// Round 3
// 492.140 us; speedup vs baseline: 1.1204x; 1.1204x over previous
//
#include <hip/hip_runtime.h>

#define Nn 100000
#define Ee 1600000
#define IND 256
#define HD 128
#define NCLS 40
#define NBLK 391   // ceil(Nn/256)

typedef _Float16 f16;
typedef f16 f16x8 __attribute__((ext_vector_type(8)));
typedef f16 f16x4 __attribute__((ext_vector_type(4)));
typedef float f32x4 __attribute__((ext_vector_type(4)));

// ---------------------------------------------------------------------------
// CSR build: histogram -> exclusive scan -> bucket scatter.
// ---------------------------------------------------------------------------
extern "C" __global__ void __launch_bounds__(256)
k_hist(const int* __restrict__ ei, int* __restrict__ counts) {
    int e = blockIdx.x * 256 + threadIdx.x;
    if (e < Ee) atomicAdd(&counts[ei[Ee + e]], 1);
}

extern "C" __global__ void __launch_bounds__(256)
k_scan1(const int* __restrict__ counts, int* __restrict__ bsum) {
    __shared__ int s[256];
    int t = threadIdx.x;
    int i = blockIdx.x * 256 + t;
    s[t] = (i < Nn) ? counts[i] : 0;
    __syncthreads();
    for (int d = 128; d > 0; d >>= 1) {
        if (t < d) s[t] += s[t + d];
        __syncthreads();
    }
    if (t == 0) bsum[blockIdx.x] = s[0];
}

extern "C" __global__ void __launch_bounds__(512)
k_scan2(int* __restrict__ bsum) {
    __shared__ int s[512];
    int t = threadIdx.x;
    int v = (t < NBLK) ? bsum[t] : 0;
    s[t] = v;
    __syncthreads();
    for (int d = 1; d < 512; d <<= 1) {
        int x = (t >= d) ? s[t - d] : 0;
        __syncthreads();
        s[t] += x;
        __syncthreads();
    }
    if (t < NBLK) bsum[t] = s[t] - v;
}

extern "C" __global__ void __launch_bounds__(256)
k_scan3(const int* __restrict__ counts, const int* __restrict__ bsum,
        int* __restrict__ offsets) {
    __shared__ int s[256];
    int t = threadIdx.x;
    int i = blockIdx.x * 256 + t;
    int v = (i < Nn) ? counts[i] : 0;
    s[t] = v;
    __syncthreads();
    for (int d = 1; d < 256; d <<= 1) {
        int x = (t >= d) ? s[t - d] : 0;
        __syncthreads();
        s[t] += x;
        __syncthreads();
    }
    if (i < Nn) offsets[i] = bsum[blockIdx.x] + s[t] - v;
    if (i == 0) offsets[Nn] = Ee;
}

// scatter: slot allocation via atomicSub on counts (counts dead after scan3;
// within-segment order is irrelevant for a sum).
extern "C" __global__ void __launch_bounds__(256)
k_scatter(const int* __restrict__ ei, const int* __restrict__ offsets,
          int* __restrict__ counts, int* __restrict__ bucket) {
    int e = blockIdx.x * 256 + threadIdx.x;
    if (e >= Ee) return;
    int dst = ei[Ee + e];
    int r = atomicSub(&counts[dst], 1);
    bucket[offsets[dst] + r - 1] = ei[e];
}

// ---------------------------------------------------------------------------
// Fused prep: weight pack (idx < 120832) + emb fp32->f16 (rest).
// wpack layout: P[((ft*KT+kt)*64+L)*8+j] = W[kt*32+(L>>4)*8+j][ft*16+(L&15)]
// Both ranges are multiples of 256 -> wave-uniform branches.
// ---------------------------------------------------------------------------
extern "C" __global__ void __launch_bounds__(256)
k_prep(const float* __restrict__ wx1, const float* __restrict__ wx2,
       const float* __restrict__ wa1, const float* __restrict__ wa2,
       const float* __restrict__ ww1, const float* __restrict__ wc,
       f16* __restrict__ wp,
       const float* __restrict__ emb, f16* __restrict__ embh) {
    int idx = blockIdx.x * 256 + threadIdx.x;
    if (idx >= 120832) {
        // emb conversion: 8 elems/thread
        int i = idx - 120832;
        const float4* p = (const float4*)emb + (size_t)i * 2;
        float4 a = p[0], b = p[1];
        f16x8 h;
        h[0] = (f16)a.x; h[1] = (f16)a.y; h[2] = (f16)a.z; h[3] = (f16)a.w;
        h[4] = (f16)b.x; h[5] = (f16)b.y; h[6] = (f16)b.z; h[7] = (f16)b.w;
        *(f16x8*)(embh + (size_t)i * 8) = h;
        return;
    }
    const float* W;
    int K, base;
    if (idx < 32768)       { W = wx1; K = 256; base = 0; }
    else if (idx < 49152)  { W = wx2; K = 128; base = 32768; }
    else if (idx < 65536)  { W = wa1; K = 128; base = 49152; }
    else if (idx < 81920)  { W = wa2; K = 128; base = 65536; }
    else if (idx < 114688) { W = ww1; K = 256; base = 81920; }
    else {
        // wc: [HD][NCLS] row-major, padded to 48 cols (3 ftiles), KT=4
        int local = idx - 114688;   // < 6144
        int j = local & 7;
        int L = (local >> 3) & 63;
        int kt = (local >> 9) & 3;
        int ft = local / 2048;
        int k = kt * 32 + (L >> 4) * 8 + j;
        int n = ft * 16 + (L & 15);
        wp[idx] = (n < NCLS) ? (f16)wc[k * NCLS + n] : (f16)0.f;
        return;
    }
    int local = idx - base;
    int KT = K >> 5;
    int j = local & 7;
    int L = (local >> 3) & 63;
    int kt = (local >> 9) % KT;
    int ft = local / (512 * KT);
    int k = kt * 32 + (L >> 4) * 8 + j;
    int n = ft * 16 + (L & 15);
    wp[idx] = (f16)W[k * HD + n];
}

// ---------------------------------------------------------------------------
// Gather-mean over f16 embeddings: one wave per node, quarter-wave per edge
// slot (16 lanes x f16x8 = 256B row). Bucket indices for the whole segment
// preloaded in one coalesced read (bucket[beg+lane]), distributed via __shfl.
// Summation order identical to the R1 kernel (2-deep, stride 8 per quarter
// wave) to keep numerics bit-stable vs the 0.0156-absmax version.
// Output: MFMA A-frag packed layout (unchanged):
//   harawp[((nt*4+kt)*64 + m + 16*q2)*8 + j],  col = kt*32 + q2*8 + j.
// ---------------------------------------------------------------------------
extern "C" __global__ void __launch_bounds__(256)
k_gather(const int* __restrict__ offsets, const int* __restrict__ bucket,
         const f16* __restrict__ embh, f16* __restrict__ harawp) {
    int t = threadIdx.x;
    int lane = t & 63;
    int node = blockIdx.x * 4 + (t >> 6);
    int q = lane >> 4;          // quarter-wave id: edge slot
    int cl = (lane & 15) * 8;   // column base (8 cols per lane)

    int beg = offsets[node];
    int end = offsets[node + 1];
    int deg = end - beg;

    // one coalesced load covers the first 64 edge indices of this node
    int myidx = (lane < deg) ? bucket[beg + lane] : 0;

    float s[8];
#pragma unroll
    for (int j = 0; j < 8; j++) s[j] = 0.f;

    int dlim = (deg < 64) ? deg : 64;
    int e = q;
    for (; e + 4 < dlim; e += 8) {         // 2 gathers in flight (R1 order)
        int a0 = __shfl(myidx, e);
        int a1 = __shfl(myidx, e + 4);
        f16x8 v0 = *(const f16x8*)(embh + (size_t)a0 * HD + cl);
        f16x8 v1 = *(const f16x8*)(embh + (size_t)a1 * HD + cl);
#pragma unroll
        for (int j = 0; j < 8; j++) s[j] += (float)v0[j] + (float)v1[j];
    }
    if (e < dlim) {
        int a0 = __shfl(myidx, e);
        f16x8 v0 = *(const f16x8*)(embh + (size_t)a0 * HD + cl);
#pragma unroll
        for (int j = 0; j < 8; j++) s[j] += (float)v0[j];
    }
    // rare tail: degree beyond 64 (Poisson(16) -> ~never, but correct)
    for (int i = beg + 64 + q; i < end; i += 4) {
        int a0 = bucket[i];
        f16x8 v0 = *(const f16x8*)(embh + (size_t)a0 * HD + cl);
#pragma unroll
        for (int j = 0; j < 8; j++) s[j] += (float)v0[j];
    }

    // reduce across the 4 quarter-waves (lanes l, l+16, l+32, l+48)
#pragma unroll
    for (int j = 0; j < 8; j++) {
        s[j] += __shfl_down(s[j], 32);
        s[j] += __shfl_down(s[j], 16);
    }

    if (lane < 16) {
        float inv = 1.0f / fmaxf((float)deg, 1.0f);
        f16x8 h;
#pragma unroll
        for (int j = 0; j < 8; j++) h[j] = (f16)(s[j] * inv);
        int nt = node >> 4, m = node & 15;
        int kt = lane >> 2, q2 = lane & 3;
        *(f16x8*)(harawp + (((nt * 4 + kt) * 64 + m + 16 * q2) * 8)) = h;
    }
}

// ---------------------------------------------------------------------------
// Fused MLP, all-MFMA. 32 nodes/block, 4 waves: mt=wid>>1 (node 16-tile),
// fh=wid&1 (feature half). A-frags: x + haraw direct from global (coalesced,
// f16-packed for haraw, fp32+cvt for x); B-frags: packed weights from global
// (L2-hot). LDS 24KB. launch_bounds(256,4): VGPR cap ~128 so step2 can hold
// all 16 x float4 loads in flight (at (256,5)/48VGPR the loads serialized ->
// latency-bound at 1.4 TB/s; (256,6) spilled to scratch, +130MB traffic).
// Residual hx+ha kept in registers (same C-tile mapping across steps).
// ---------------------------------------------------------------------------
extern "C" __global__ void __launch_bounds__(256, 4)
linkx_mlp(const float* __restrict__ x, const f16* __restrict__ harawp,
          const f16* __restrict__ wx1p, const float* __restrict__ bx1,
          const f16* __restrict__ wx2p, const float* __restrict__ bx2,
          const f16* __restrict__ wa1p, const float* __restrict__ ba1,
          const f16* __restrict__ wa2p, const float* __restrict__ ba2,
          const f16* __restrict__ ww1p, const float* __restrict__ bw1,
          const f16* __restrict__ wcp, const float* __restrict__ bc,
          float* __restrict__ out) {
    __shared__ __align__(16) f16 shr[4096];   // t1p / t2p / h2p (8KB shared)
    __shared__ __align__(16) f16 hxp[4096];   // hx packed (8KB)
    __shared__ __align__(16) f16 hap[4096];   // ha packed (8KB)

    const int t = threadIdx.x;
    const int node0 = blockIdx.x * 32;
    const int lane = t & 63;
    const int wid = t >> 6;
    const int mt = wid >> 1;
    const int fh = wid & 1;

    f32x4 acc[4];
    float rreg[4][4];   // hx+ha residual, same C-tile as acc

#define INIT_ACC(BIAS)                                                    \
    _Pragma("unroll")                                                     \
    for (int q = 0; q < 4; q++) {                                         \
        float bv = (BIAS)[(fh * 4 + q) * 16 + (lane & 15)];               \
        acc[q][0] = bv; acc[q][1] = bv; acc[q][2] = bv; acc[q][3] = bv;   \
    }

#define GEMM_K128(APACK, BP)                                                  \
    _Pragma("unroll")                                                         \
    for (int kt = 0; kt < 4; kt++) {                                          \
        f16x8 a = *(const f16x8*)((APACK) + ((mt * 4 + kt) * 64 + lane) * 8); \
        _Pragma("unroll")                                                     \
        for (int q = 0; q < 4; q++) {                                         \
            f16x8 b = *(const f16x8*)((BP) + (((fh*4+q)*4 + kt)*64 + lane)*8);\
            acc[q] = __builtin_amdgcn_mfma_f32_16x16x32_f16(a, b, acc[q], 0, 0, 0); \
        }                                                                     \
    }

    // Epilogue -> packed LDS dst; MODE 0: relu, 1: no relu + rreg=v,
    // 2: no relu + rreg+=v, 3: h=relu(acc); v=relu(h+rreg)
#define EPILOGUE(MODE, PDST)                                                  \
    _Pragma("unroll")                                                         \
    for (int q = 0; q < 4; q++) {                                             \
        int f = (fh * 4 + q) * 16 + (lane & 15);                              \
        int kt2 = f >> 5, q2 = (f >> 3) & 3, j2 = f & 7;                      \
        _Pragma("unroll")                                                     \
        for (int r = 0; r < 4; r++) {                                         \
            int n = (lane >> 4) * 4 + r;                                      \
            float v = acc[q][r];                                              \
            if (MODE == 0) v = fmaxf(v, 0.f);                                 \
            if (MODE == 1) rreg[q][r] = v;                                    \
            if (MODE == 2) rreg[q][r] += v;                                   \
            if (MODE == 3) v = fmaxf(fmaxf(v, 0.f) + rreg[q][r], 0.f);        \
            (PDST)[((mt * 4 + kt2) * 64 + n + 16 * q2) * 8 + j2] = (f16)v;    \
        }                                                                     \
    }

    // step2: t1 = relu(x @ wx1 + bx1), K=256; A from global x (fp32->f16).
    // All 16 float4 x-loads hoisted ahead of the MFMA loop for deep ILP.
    INIT_ACC(bx1)
    {
        const float* xbase = x + (size_t)(node0 + mt * 16 + (lane & 15)) * IND
                               + (lane >> 4) * 8;
        float4 u[16];
#pragma unroll
        for (int kt = 0; kt < 8; kt++) {
            u[2 * kt]     = *(const float4*)(xbase + kt * 32);
            u[2 * kt + 1] = *(const float4*)(xbase + kt * 32 + 4);
        }
#pragma unroll
        for (int kt = 0; kt < 8; kt++) {
            float4 u0 = u[2 * kt], u1 = u[2 * kt + 1];
            f16x8 a;
            a[0] = (f16)u0.x; a[1] = (f16)u0.y; a[2] = (f16)u0.z; a[3] = (f16)u0.w;
            a[4] = (f16)u1.x; a[5] = (f16)u1.y; a[6] = (f16)u1.z; a[7] = (f16)u1.w;
#pragma unroll
            for (int q = 0; q < 4; q++) {
                f16x8 b = *(const f16x8*)(wx1p + (((fh*4+q)*8 + kt)*64 + lane)*8);
                acc[q] = __builtin_amdgcn_mfma_f32_16x16x32_f16(a, b, acc[q], 0, 0, 0);
            }
        }
    }
    EPILOGUE(0, shr)          // t1p
    __syncthreads();

    // step3: hx = t1 @ wx2 + bx2 -> hxp, rreg = hx
    INIT_ACC(bx2)
    GEMM_K128(shr, wx2p)
    EPILOGUE(1, hxp)
    __syncthreads();          // t1p reads done -> shr reusable

    // step5: t2 = relu(haraw @ wa1 + ba1); A direct from global packed f16,
    // all 4 A-frags hoisted (L3-latency loads).
    INIT_ACC(ba1)
    {
        int ntb = (node0 >> 4) + mt;
        f16x8 av[4];
#pragma unroll
        for (int kt = 0; kt < 4; kt++)
            av[kt] = *(const f16x8*)(harawp + ((ntb * 4 + kt) * 64 + lane) * 8);
#pragma unroll
        for (int kt = 0; kt < 4; kt++) {
#pragma unroll
            for (int q = 0; q < 4; q++) {
                f16x8 b = *(const f16x8*)(wa1p + (((fh*4+q)*4 + kt)*64 + lane)*8);
                acc[q] = __builtin_amdgcn_mfma_f32_16x16x32_f16(av[kt], b, acc[q], 0, 0, 0);
            }
        }
    }
    EPILOGUE(0, shr)          // t2p
    __syncthreads();

    // step6: ha = t2 @ wa2 + ba2 -> hap, rreg += ha
    INIT_ACC(ba2)
    GEMM_K128(shr, wa2p)
    EPILOGUE(2, hap)
    __syncthreads();          // t2p reads done -> shr reusable

    // step7+8: h2 = relu(relu([hx|ha] @ ww1 + bw1) + hx + ha) -> h2p
    INIT_ACC(bw1)
#pragma unroll
    for (int kt = 0; kt < 8; kt++) {
        const f16* ap = (kt < 4) ? (hxp + ((mt * 4 + kt) * 64 + lane) * 8)
                                 : (hap + ((mt * 4 + (kt - 4)) * 64 + lane) * 8);
        f16x8 a = *(const f16x8*)ap;
#pragma unroll
        for (int q = 0; q < 4; q++) {
            f16x8 b = *(const f16x8*)(ww1p + (((fh*4+q)*8 + kt)*64 + lane)*8);
            acc[q] = __builtin_amdgcn_mfma_f32_16x16x32_f16(a, b, acc[q], 0, 0, 0);
        }
    }
    EPILOGUE(3, shr)          // h2p
    __syncthreads();

    // step9: logits = h2 @ wc + bc (MFMA, 3 ftiles: fh0 -> {0,2}, fh1 -> {1})
    {
        int nft = (fh == 0) ? 2 : 1;
#pragma unroll 2
        for (int ii = 0; ii < nft; ii++) {
            int ft = (ii == 0) ? fh : 2;
            int f = ft * 16 + (lane & 15);
            f32x4 c;
            float bv = (f < NCLS) ? bc[f] : 0.f;
            c[0] = bv; c[1] = bv; c[2] = bv; c[3] = bv;
#pragma unroll
            for (int kt = 0; kt < 4; kt++) {
                f16x8 a = *(const f16x8*)(shr + ((mt * 4 + kt) * 64 + lane) * 8);
                f16x8 b = *(const f16x8*)(wcp + ((ft * 4 + kt) * 64 + lane) * 8);
                c = __builtin_amdgcn_mfma_f32_16x16x32_f16(a, b, c, 0, 0, 0);
            }
            if (f < NCLS) {
#pragma unroll
                for (int r = 0; r < 4; r++) {
                    int n = node0 + mt * 16 + (lane >> 4) * 4 + r;
                    out[(size_t)n * NCLS + f] = c[r];
                }
            }
        }
    }
}

extern "C" void kernel_launch(void* const* d_in, const int* in_sizes, int n_in,
                              void* d_out, int out_size, void* d_ws, size_t ws_size,
                              hipStream_t stream) {
    const float* x   = (const float*)d_in[0];
    const int*   ei  = (const int*)d_in[1];
    const float* emb = (const float*)d_in[2];
    const float* wx1 = (const float*)d_in[3];
    const float* bx1 = (const float*)d_in[4];
    const float* wx2 = (const float*)d_in[5];
    const float* bx2 = (const float*)d_in[6];
    const float* wa1 = (const float*)d_in[7];
    const float* ba1 = (const float*)d_in[8];
    const float* wa2 = (const float*)d_in[9];
    const float* ba2 = (const float*)d_in[10];
    const float* ww1 = (const float*)d_in[11];
    const float* bw1 = (const float*)d_in[12];
    const float* wc  = (const float*)d_in[13];
    const float* bc  = (const float*)d_in[14];
    float* out = (float*)d_out;

    int* ws = (int*)d_ws;
    int* counts  = ws;                 // [Nn]  (also scatter slot allocator)
    int* offsets = ws + 2 * Nn;        // [Nn+1]
    int* bsum    = ws + 3 * Nn + 16;   // [NBLK]
    int* bucket  = ws + 3 * Nn + 512;  // [Ee]
    f16* wp      = (f16*)(ws + 3 * Nn + 512 + Ee);  // 120832 f16 (16B aligned)
    f16* wx1p = wp;                 // 32768
    f16* wx2p = wp + 32768;         // 16384
    f16* wa1p = wp + 49152;         // 16384
    f16* wa2p = wp + 65536;         // 16384
    f16* ww1p = wp + 81920;         // 32768
    f16* wcp  = wp + 114688;        // 6144
    f16* harawp = wp + 131072;                       // [Nn*HD] f16, A-packed
    f16* embh   = harawp + (size_t)Nn * HD;          // [Nn*HD] f16, linear

    hipMemsetAsync(ws, 0, (size_t)Nn * sizeof(int), stream);

    // prep: wpack (472 blocks worth) + embconv (6250 blocks worth), fused
    k_prep<<<6722, 256, 0, stream>>>(wx1, wx2, wa1, wa2, ww1, wc, wp, emb, embh);
    k_hist<<<Ee / 256, 256, 0, stream>>>(ei, counts);
    k_scan1<<<NBLK, 256, 0, stream>>>(counts, bsum);
    k_scan2<<<1, 512, 0, stream>>>(bsum);
    k_scan3<<<NBLK, 256, 0, stream>>>(counts, bsum, offsets);
    k_scatter<<<Ee / 256, 256, 0, stream>>>(ei, offsets, counts, bucket);
    k_gather<<<Nn / 4, 256, 0, stream>>>(offsets, bucket, embh, harawp);

    linkx_mlp<<<Nn / 32, 256, 0, stream>>>(x, harawp,
                                           wx1p, bx1, wx2p, bx2,
                                           wa1p, ba1, wa2p, ba2,
                                           ww1p, bw1, wcp, bc, out);
}

// Round 4
// 428.437 us; speedup vs baseline: 1.2870x; 1.1487x over previous
//
#include <hip/hip_runtime.h>

#define Nn 100000
#define Ee 1600000
#define IND 256
#define HD 128
#define NCLS 40
#define NBLK 391   // ceil(Nn/256)

typedef _Float16 f16;
typedef f16 f16x8 __attribute__((ext_vector_type(8)));
typedef f16 f16x4 __attribute__((ext_vector_type(4)));
typedef float f32x4 __attribute__((ext_vector_type(4)));

// ---------------------------------------------------------------------------
// Fused prep + hist-rank pass (single atomic pass of the CSR build).
// Block interleave: bid<12500 alternates hist/prep; bid>=12500 -> prep tail.
//   hist-rank: rank[e] = atomicAdd(&counts[dst], 1)   (1.6M atomics, the ONLY
//              atomic pass; rank doubles as within-segment slot for scatter)
//   prep: weight pack (idx < 120832) + emb fp32->f16 (rest), as before.
// wpack layout: P[((ft*KT+kt)*64+L)*8+j] = W[kt*32+(L>>4)*8+j][ft*16+(L&15)]
// ---------------------------------------------------------------------------
extern "C" __global__ void __launch_bounds__(256)
k_prep(const float* __restrict__ wx1, const float* __restrict__ wx2,
       const float* __restrict__ wa1, const float* __restrict__ wa2,
       const float* __restrict__ ww1, const float* __restrict__ wc,
       f16* __restrict__ wp,
       const float* __restrict__ emb, f16* __restrict__ embh,
       const int* __restrict__ ei, int* __restrict__ counts,
       int* __restrict__ rank) {
    int bid = blockIdx.x;
    int p;
    if (bid < 12500) {
        if (bid & 1) {
            // hist-rank block
            int e = (bid >> 1) * 256 + threadIdx.x;
            int dst = ei[Ee + e];
            rank[e] = atomicAdd(&counts[dst], 1);
            return;
        }
        p = bid >> 1;
    } else {
        p = 6250 + (bid - 12500);
    }
    int idx = p * 256 + threadIdx.x;
    if (idx >= 120832) {
        // emb conversion: 8 elems/thread
        int i = idx - 120832;
        const float4* pp = (const float4*)emb + (size_t)i * 2;
        float4 a = pp[0], b = pp[1];
        f16x8 h;
        h[0] = (f16)a.x; h[1] = (f16)a.y; h[2] = (f16)a.z; h[3] = (f16)a.w;
        h[4] = (f16)b.x; h[5] = (f16)b.y; h[6] = (f16)b.z; h[7] = (f16)b.w;
        *(f16x8*)(embh + (size_t)i * 8) = h;
        return;
    }
    const float* W;
    int K, base;
    if (idx < 32768)       { W = wx1; K = 256; base = 0; }
    else if (idx < 49152)  { W = wx2; K = 128; base = 32768; }
    else if (idx < 65536)  { W = wa1; K = 128; base = 49152; }
    else if (idx < 81920)  { W = wa2; K = 128; base = 65536; }
    else if (idx < 114688) { W = ww1; K = 256; base = 81920; }
    else {
        // wc: [HD][NCLS] row-major, padded to 48 cols (3 ftiles), KT=4
        int local = idx - 114688;   // < 6144
        int j = local & 7;
        int L = (local >> 3) & 63;
        int kt = (local >> 9) & 3;
        int ft = local / 2048;
        int k = kt * 32 + (L >> 4) * 8 + j;
        int n = ft * 16 + (L & 15);
        wp[idx] = (n < NCLS) ? (f16)wc[k * NCLS + n] : (f16)0.f;
        return;
    }
    int local = idx - base;
    int KT = K >> 5;
    int j = local & 7;
    int L = (local >> 3) & 63;
    int kt = (local >> 9) % KT;
    int ft = local / (512 * KT);
    int k = kt * 32 + (L >> 4) * 8 + j;
    int n = ft * 16 + (L & 15);
    wp[idx] = (f16)W[k * HD + n];
}

extern "C" __global__ void __launch_bounds__(256)
k_scan1(const int* __restrict__ counts, int* __restrict__ bsum) {
    __shared__ int s[256];
    int t = threadIdx.x;
    int i = blockIdx.x * 256 + t;
    s[t] = (i < Nn) ? counts[i] : 0;
    __syncthreads();
    for (int d = 128; d > 0; d >>= 1) {
        if (t < d) s[t] += s[t + d];
        __syncthreads();
    }
    if (t == 0) bsum[blockIdx.x] = s[0];
}

// scan3 with fused scan2: each block reduces bsum[0..bid) itself (<=391 ints)
extern "C" __global__ void __launch_bounds__(256)
k_scan3(const int* __restrict__ counts, const int* __restrict__ bsum,
        int* __restrict__ offsets) {
    __shared__ int s[256];
    __shared__ int basev;
    int t = threadIdx.x;
    int i = blockIdx.x * 256 + t;
    // sum of bsum[0..blockIdx.x)
    int partial = 0;
    for (int k = t; k < blockIdx.x; k += 256) partial += bsum[k];
    s[t] = partial;
    __syncthreads();
    for (int d = 128; d > 0; d >>= 1) {
        if (t < d) s[t] += s[t + d];
        __syncthreads();
    }
    if (t == 0) basev = s[0];
    __syncthreads();
    // local exclusive scan of counts
    int v = (i < Nn) ? counts[i] : 0;
    s[t] = v;
    __syncthreads();
    for (int d = 1; d < 256; d <<= 1) {
        int x = (t >= d) ? s[t - d] : 0;
        __syncthreads();
        s[t] += x;
        __syncthreads();
    }
    if (i < Nn) offsets[i] = basev + s[t] - v;
    if (i == 0) offsets[Nn] = Ee;
}

// pass 2: atomic-free scatter using precomputed ranks
extern "C" __global__ void __launch_bounds__(256)
k_scatter2(const int* __restrict__ ei, const int* __restrict__ offsets,
           const int* __restrict__ rank, int* __restrict__ bucket) {
    int e = blockIdx.x * 256 + threadIdx.x;
    int dst = ei[Ee + e];
    bucket[offsets[dst] + rank[e]] = ei[e];
}

// ---------------------------------------------------------------------------
// Gather-mean over f16 embeddings: one wave per node, quarter-wave per edge
// slot (16 lanes x f16x8 = 256B row). Bucket indices for the whole segment
// preloaded in one coalesced read (bucket[beg+lane]), distributed via __shfl.
// Output: MFMA A-frag packed layout:
//   harawp[((nt*4+kt)*64 + m + 16*q2)*8 + j],  col = kt*32 + q2*8 + j.
// ---------------------------------------------------------------------------
extern "C" __global__ void __launch_bounds__(256)
k_gather(const int* __restrict__ offsets, const int* __restrict__ bucket,
         const f16* __restrict__ embh, f16* __restrict__ harawp) {
    int t = threadIdx.x;
    int lane = t & 63;
    int node = blockIdx.x * 4 + (t >> 6);
    int q = lane >> 4;          // quarter-wave id: edge slot
    int cl = (lane & 15) * 8;   // column base (8 cols per lane)

    int beg = offsets[node];
    int end = offsets[node + 1];
    int deg = end - beg;

    // one coalesced load covers the first 64 edge indices of this node
    int myidx = (lane < deg) ? bucket[beg + lane] : 0;

    float s[8];
#pragma unroll
    for (int j = 0; j < 8; j++) s[j] = 0.f;

    int dlim = (deg < 64) ? deg : 64;
    int e = q;
    for (; e + 4 < dlim; e += 8) {         // 2 gathers in flight
        int a0 = __shfl(myidx, e);
        int a1 = __shfl(myidx, e + 4);
        f16x8 v0 = *(const f16x8*)(embh + (size_t)a0 * HD + cl);
        f16x8 v1 = *(const f16x8*)(embh + (size_t)a1 * HD + cl);
#pragma unroll
        for (int j = 0; j < 8; j++) s[j] += (float)v0[j] + (float)v1[j];
    }
    if (e < dlim) {
        int a0 = __shfl(myidx, e);
        f16x8 v0 = *(const f16x8*)(embh + (size_t)a0 * HD + cl);
#pragma unroll
        for (int j = 0; j < 8; j++) s[j] += (float)v0[j];
    }
    // rare tail: degree beyond 64 (Poisson(16) -> ~never, but correct)
    for (int i = beg + 64 + q; i < end; i += 4) {
        int a0 = bucket[i];
        f16x8 v0 = *(const f16x8*)(embh + (size_t)a0 * HD + cl);
#pragma unroll
        for (int j = 0; j < 8; j++) s[j] += (float)v0[j];
    }

    // reduce across the 4 quarter-waves (lanes l, l+16, l+32, l+48)
#pragma unroll
    for (int j = 0; j < 8; j++) {
        s[j] += __shfl_down(s[j], 32);
        s[j] += __shfl_down(s[j], 16);
    }

    if (lane < 16) {
        float inv = 1.0f / fmaxf((float)deg, 1.0f);
        f16x8 h;
#pragma unroll
        for (int j = 0; j < 8; j++) h[j] = (f16)(s[j] * inv);
        int nt = node >> 4, m = node & 15;
        int kt = lane >> 2, q2 = lane & 3;
        *(f16x8*)(harawp + (((nt * 4 + kt) * 64 + m + 16 * q2) * 8)) = h;
    }
}

// ---------------------------------------------------------------------------
// Fused MLP, all-MFMA. 32 nodes/block, 4 waves: mt=wid>>1 (node 16-tile),
// fh=wid&1 (feature half). A-frags: x + haraw direct from global (coalesced,
// f16-packed for haraw, fp32+cvt for x); B-frags: packed weights from global
// (L2-hot). LDS 24KB. launch_bounds(256,4): VGPR cap ~128 so step2 can hold
// all 16 x float4 loads in flight ((256,5)/48VGPR serialized the loads;
// (256,6) spilled to scratch, +130MB traffic).
// Residual hx+ha kept in registers (same C-tile mapping across steps).
// ---------------------------------------------------------------------------
extern "C" __global__ void __launch_bounds__(256, 4)
linkx_mlp(const float* __restrict__ x, const f16* __restrict__ harawp,
          const f16* __restrict__ wx1p, const float* __restrict__ bx1,
          const f16* __restrict__ wx2p, const float* __restrict__ bx2,
          const f16* __restrict__ wa1p, const float* __restrict__ ba1,
          const f16* __restrict__ wa2p, const float* __restrict__ ba2,
          const f16* __restrict__ ww1p, const float* __restrict__ bw1,
          const f16* __restrict__ wcp, const float* __restrict__ bc,
          float* __restrict__ out) {
    __shared__ __align__(16) f16 shr[4096];   // t1p / t2p / h2p (8KB shared)
    __shared__ __align__(16) f16 hxp[4096];   // hx packed (8KB)
    __shared__ __align__(16) f16 hap[4096];   // ha packed (8KB)

    const int t = threadIdx.x;
    const int node0 = blockIdx.x * 32;
    const int lane = t & 63;
    const int wid = t >> 6;
    const int mt = wid >> 1;
    const int fh = wid & 1;

    f32x4 acc[4];
    float rreg[4][4];   // hx+ha residual, same C-tile as acc

#define INIT_ACC(BIAS)                                                    \
    _Pragma("unroll")                                                     \
    for (int q = 0; q < 4; q++) {                                         \
        float bv = (BIAS)[(fh * 4 + q) * 16 + (lane & 15)];               \
        acc[q][0] = bv; acc[q][1] = bv; acc[q][2] = bv; acc[q][3] = bv;   \
    }

#define GEMM_K128(APACK, BP)                                                  \
    _Pragma("unroll")                                                         \
    for (int kt = 0; kt < 4; kt++) {                                          \
        f16x8 a = *(const f16x8*)((APACK) + ((mt * 4 + kt) * 64 + lane) * 8); \
        _Pragma("unroll")                                                     \
        for (int q = 0; q < 4; q++) {                                         \
            f16x8 b = *(const f16x8*)((BP) + (((fh*4+q)*4 + kt)*64 + lane)*8);\
            acc[q] = __builtin_amdgcn_mfma_f32_16x16x32_f16(a, b, acc[q], 0, 0, 0); \
        }                                                                     \
    }

    // Epilogue -> packed LDS dst; MODE 0: relu, 1: no relu + rreg=v,
    // 2: no relu + rreg+=v, 3: h=relu(acc); v=relu(h+rreg)
#define EPILOGUE(MODE, PDST)                                                  \
    _Pragma("unroll")                                                         \
    for (int q = 0; q < 4; q++) {                                             \
        int f = (fh * 4 + q) * 16 + (lane & 15);                              \
        int kt2 = f >> 5, q2 = (f >> 3) & 3, j2 = f & 7;                      \
        _Pragma("unroll")                                                     \
        for (int r = 0; r < 4; r++) {                                         \
            int n = (lane >> 4) * 4 + r;                                      \
            float v = acc[q][r];                                              \
            if (MODE == 0) v = fmaxf(v, 0.f);                                 \
            if (MODE == 1) rreg[q][r] = v;                                    \
            if (MODE == 2) rreg[q][r] += v;                                   \
            if (MODE == 3) v = fmaxf(fmaxf(v, 0.f) + rreg[q][r], 0.f);        \
            (PDST)[((mt * 4 + kt2) * 64 + n + 16 * q2) * 8 + j2] = (f16)v;    \
        }                                                                     \
    }

    // step2: t1 = relu(x @ wx1 + bx1), K=256; A from global x (fp32->f16).
    // All 16 float4 x-loads hoisted ahead of the MFMA loop for deep ILP.
    INIT_ACC(bx1)
    {
        const float* xbase = x + (size_t)(node0 + mt * 16 + (lane & 15)) * IND
                               + (lane >> 4) * 8;
        float4 u[16];
#pragma unroll
        for (int kt = 0; kt < 8; kt++) {
            u[2 * kt]     = *(const float4*)(xbase + kt * 32);
            u[2 * kt + 1] = *(const float4*)(xbase + kt * 32 + 4);
        }
#pragma unroll
        for (int kt = 0; kt < 8; kt++) {
            float4 u0 = u[2 * kt], u1 = u[2 * kt + 1];
            f16x8 a;
            a[0] = (f16)u0.x; a[1] = (f16)u0.y; a[2] = (f16)u0.z; a[3] = (f16)u0.w;
            a[4] = (f16)u1.x; a[5] = (f16)u1.y; a[6] = (f16)u1.z; a[7] = (f16)u1.w;
#pragma unroll
            for (int q = 0; q < 4; q++) {
                f16x8 b = *(const f16x8*)(wx1p + (((fh*4+q)*8 + kt)*64 + lane)*8);
                acc[q] = __builtin_amdgcn_mfma_f32_16x16x32_f16(a, b, acc[q], 0, 0, 0);
            }
        }
    }
    EPILOGUE(0, shr)          // t1p
    __syncthreads();

    // step3: hx = t1 @ wx2 + bx2 -> hxp, rreg = hx
    INIT_ACC(bx2)
    GEMM_K128(shr, wx2p)
    EPILOGUE(1, hxp)
    __syncthreads();          // t1p reads done -> shr reusable

    // step5: t2 = relu(haraw @ wa1 + ba1); A direct from global packed f16,
    // all 4 A-frags hoisted (L3-latency loads).
    INIT_ACC(ba1)
    {
        int ntb = (node0 >> 4) + mt;
        f16x8 av[4];
#pragma unroll
        for (int kt = 0; kt < 4; kt++)
            av[kt] = *(const f16x8*)(harawp + ((ntb * 4 + kt) * 64 + lane) * 8);
#pragma unroll
        for (int kt = 0; kt < 4; kt++) {
#pragma unroll
            for (int q = 0; q < 4; q++) {
                f16x8 b = *(const f16x8*)(wa1p + (((fh*4+q)*4 + kt)*64 + lane)*8);
                acc[q] = __builtin_amdgcn_mfma_f32_16x16x32_f16(av[kt], b, acc[q], 0, 0, 0);
            }
        }
    }
    EPILOGUE(0, shr)          // t2p
    __syncthreads();

    // step6: ha = t2 @ wa2 + ba2 -> hap, rreg += ha
    INIT_ACC(ba2)
    GEMM_K128(shr, wa2p)
    EPILOGUE(2, hap)
    __syncthreads();          // t2p reads done -> shr reusable

    // step7+8: h2 = relu(relu([hx|ha] @ ww1 + bw1) + hx + ha) -> h2p
    INIT_ACC(bw1)
#pragma unroll
    for (int kt = 0; kt < 8; kt++) {
        const f16* ap = (kt < 4) ? (hxp + ((mt * 4 + kt) * 64 + lane) * 8)
                                 : (hap + ((mt * 4 + (kt - 4)) * 64 + lane) * 8);
        f16x8 a = *(const f16x8*)ap;
#pragma unroll
        for (int q = 0; q < 4; q++) {
            f16x8 b = *(const f16x8*)(ww1p + (((fh*4+q)*8 + kt)*64 + lane)*8);
            acc[q] = __builtin_amdgcn_mfma_f32_16x16x32_f16(a, b, acc[q], 0, 0, 0);
        }
    }
    EPILOGUE(3, shr)          // h2p
    __syncthreads();

    // step9: logits = h2 @ wc + bc (MFMA, 3 ftiles: fh0 -> {0,2}, fh1 -> {1})
    {
        int nft = (fh == 0) ? 2 : 1;
#pragma unroll 2
        for (int ii = 0; ii < nft; ii++) {
            int ft = (ii == 0) ? fh : 2;
            int f = ft * 16 + (lane & 15);
            f32x4 c;
            float bv = (f < NCLS) ? bc[f] : 0.f;
            c[0] = bv; c[1] = bv; c[2] = bv; c[3] = bv;
#pragma unroll
            for (int kt = 0; kt < 4; kt++) {
                f16x8 a = *(const f16x8*)(shr + ((mt * 4 + kt) * 64 + lane) * 8);
                f16x8 b = *(const f16x8*)(wcp + ((ft * 4 + kt) * 64 + lane) * 8);
                c = __builtin_amdgcn_mfma_f32_16x16x32_f16(a, b, c, 0, 0, 0);
            }
            if (f < NCLS) {
#pragma unroll
                for (int r = 0; r < 4; r++) {
                    int n = node0 + mt * 16 + (lane >> 4) * 4 + r;
                    out[(size_t)n * NCLS + f] = c[r];
                }
            }
        }
    }
}

extern "C" void kernel_launch(void* const* d_in, const int* in_sizes, int n_in,
                              void* d_out, int out_size, void* d_ws, size_t ws_size,
                              hipStream_t stream) {
    const float* x   = (const float*)d_in[0];
    const int*   ei  = (const int*)d_in[1];
    const float* emb = (const float*)d_in[2];
    const float* wx1 = (const float*)d_in[3];
    const float* bx1 = (const float*)d_in[4];
    const float* wx2 = (const float*)d_in[5];
    const float* bx2 = (const float*)d_in[6];
    const float* wa1 = (const float*)d_in[7];
    const float* ba1 = (const float*)d_in[8];
    const float* wa2 = (const float*)d_in[9];
    const float* ba2 = (const float*)d_in[10];
    const float* ww1 = (const float*)d_in[11];
    const float* bw1 = (const float*)d_in[12];
    const float* wc  = (const float*)d_in[13];
    const float* bc  = (const float*)d_in[14];
    float* out = (float*)d_out;

    int* ws = (int*)d_ws;
    int* counts  = ws;                 // [Nn]  (atomic rank allocator)
    int* offsets = ws + 2 * Nn;        // [Nn+1]
    int* bsum    = ws + 3 * Nn + 16;   // [NBLK]
    int* bucket  = ws + 3 * Nn + 512;  // [Ee]
    f16* wp      = (f16*)(ws + 3 * Nn + 512 + Ee);  // 120832 f16 (16B aligned)
    f16* wx1p = wp;                 // 32768
    f16* wx2p = wp + 32768;         // 16384
    f16* wa1p = wp + 49152;         // 16384
    f16* wa2p = wp + 65536;         // 16384
    f16* ww1p = wp + 81920;         // 32768
    f16* wcp  = wp + 114688;        // 6144
    f16* harawp = wp + 131072;                       // [Nn*HD] f16, A-packed
    f16* embh   = harawp + (size_t)Nn * HD;          // [Nn*HD] f16, linear
    // rank[Ee] aliases harawp: rank is dead before k_gather writes harawp
    int* rank = (int*)harawp;

    hipMemsetAsync(ws, 0, (size_t)Nn * sizeof(int), stream);

    // prep (6722 block-units) + hist-rank (6250 block-units), interleaved
    k_prep<<<12972, 256, 0, stream>>>(wx1, wx2, wa1, wa2, ww1, wc, wp,
                                      emb, embh, ei, counts, rank);
    k_scan1<<<NBLK, 256, 0, stream>>>(counts, bsum);
    k_scan3<<<NBLK, 256, 0, stream>>>(counts, bsum, offsets);
    k_scatter2<<<Ee / 256, 256, 0, stream>>>(ei, offsets, rank, bucket);
    k_gather<<<Nn / 4, 256, 0, stream>>>(offsets, bucket, embh, harawp);

    linkx_mlp<<<Nn / 32, 256, 0, stream>>>(x, harawp,
                                           wx1p, bx1, wx2p, bx2,
                                           wa1p, ba1, wa2p, ba2,
                                           ww1p, bw1, wcp, bc, out);
}